// Round 9
// baseline (472.696 us; speedup 1.0000x reference)
//
#include <hip/hip_runtime.h>
#include <cstdint>
#include <cstddef>

// ---------------------------------------------------------------------------
// 2-layer GCN, bf16 intermediates. R9:
//  - UNFUSED degrank (R8 lesson: fused kernel's 64KB LDS is reserved even for
//    early-return atomic blocks -> 20% occupancy -> atomics starved. Standalone
//    degrank has no LDS, high occupancy.)
//  - scan3 dropped: consumers add boff[node>>10] on the fly
//  - edge records packed (src,norm) int2; agg loops 4-way unrolled
// ---------------------------------------------------------------------------

typedef unsigned long long u64;
typedef unsigned int u32;
typedef unsigned short u16;

__device__ __forceinline__ float bflo(u32 u) { return __uint_as_float(u << 16); }
__device__ __forceinline__ float bfhi(u32 u) { return __uint_as_float(u & 0xffff0000u); }
__device__ __forceinline__ u32 f2bf(float f) {  // round-to-nearest-even
  u32 u = __float_as_uint(f);
  return (u + 0x7fffu + ((u >> 16) & 1u)) >> 16;
}
__device__ __forceinline__ u32 pack2bf(float lo, float hi) {
  return f2bf(lo) | (f2bf(hi) << 16);
}

__global__ void init_kernel(u64* packed, int n) {
  int i = blockIdx.x * 256 + threadIdx.x;
  if (i < n) packed[i] = (1ull << 32);  // deg = 1.0 fixed-point, count = 0
}

// ---- degrank: ONE u64 atomic/edge; rank = old count (bits 48..63) ----
__global__ void degrank_kernel(const int* __restrict__ dst, const float* __restrict__ w,
                               u64* packed, u16* __restrict__ rank, int E) {
  int e = blockIdx.x * 256 + threadIdx.x;
  if (e < E) {
    int d = dst[e];
    u64 add = (1ull << 48) | (u64)(w[e] * 4294967296.0f);
    u64 old = atomicAdd(&packed[d], add);
    rank[e] = (u16)(old >> 48);
  }
}

// ---- gemm1: h1[M,128](bf16) = x[M,128](fp32) @ W1[128,128], tile 64x64 ----
__global__ __launch_bounds__(256) void gemm1_kernel(const float* __restrict__ x,
                                                    const float* __restrict__ W1,
                                                    u16* __restrict__ h1, int M) {
  __shared__ float As[128][64];  // [k][row]
  __shared__ float Ws[128][64];  // [k][col]
  const int tid = threadIdx.x;
  const int tx = tid & 15;
  const int ty = tid >> 4;
  const int rowbase = blockIdx.x * 64;
  const int colbase = blockIdx.y * 64;

  for (int i = tid; i < 64 * 32; i += 256) {
    int row = i & 63;
    int k4 = (i >> 6) << 2;
    int gr = rowbase + row;
    float4 v = make_float4(0.f, 0.f, 0.f, 0.f);
    if (gr < M) v = *reinterpret_cast<const float4*>(x + (size_t)gr * 128 + k4);
    As[k4 + 0][row] = v.x;
    As[k4 + 1][row] = v.y;
    As[k4 + 2][row] = v.z;
    As[k4 + 3][row] = v.w;
  }
  for (int i = tid; i < 128 * 16; i += 256) {
    int c4 = (i & 15) << 2;
    int k = i >> 4;
    float4 v = *reinterpret_cast<const float4*>(W1 + (size_t)k * 128 + colbase + c4);
    *reinterpret_cast<float4*>(&Ws[k][c4]) = v;
  }
  __syncthreads();

  float acc[4][4] = {};
  #pragma unroll 8
  for (int k = 0; k < 128; ++k) {
    float4 a = *reinterpret_cast<const float4*>(&As[k][ty << 2]);
    float4 b = *reinterpret_cast<const float4*>(&Ws[k][tx << 2]);
    acc[0][0] += a.x * b.x; acc[0][1] += a.x * b.y; acc[0][2] += a.x * b.z; acc[0][3] += a.x * b.w;
    acc[1][0] += a.y * b.x; acc[1][1] += a.y * b.y; acc[1][2] += a.y * b.z; acc[1][3] += a.y * b.w;
    acc[2][0] += a.z * b.x; acc[2][1] += a.z * b.y; acc[2][2] += a.z * b.z; acc[2][3] += a.z * b.w;
    acc[3][0] += a.w * b.x; acc[3][1] += a.w * b.y; acc[3][2] += a.w * b.z; acc[3][3] += a.w * b.w;
  }
  #pragma unroll
  for (int r = 0; r < 4; ++r) {
    int gr = rowbase + (ty << 2) + r;
    if (gr < M) {
      uint2 p;
      p.x = pack2bf(acc[r][0], acc[r][1]);
      p.y = pack2bf(acc[r][2], acc[r][3]);
      *reinterpret_cast<uint2*>(h1 + (size_t)gr * 128 + colbase + (tx << 2)) = p;
    }
  }
}

// ---- scan1 (+dinv): block-local exclusive scan of counts -> rowstart ----
__global__ void scan1_kernel(const u64* __restrict__ packed, int* __restrict__ rowstart,
                             int* __restrict__ bsum, float* __restrict__ dinvp, int n) {
  __shared__ int wsum[4];
  int b = blockIdx.x;
  int base = b * 1024;
  int tid = threadIdx.x;
  int lane = tid & 63, wv = tid >> 6;
  int idx = base + tid * 4;
  int v0 = 0, v1 = 0, v2 = 0, v3 = 0;
  #pragma unroll
  for (int j = 0; j < 4; ++j) {
    if (idx + j < n) {
      u64 p = packed[idx + j];
      int c = (int)(p >> 48);
      if (j == 0) v0 = c; else if (j == 1) v1 = c; else if (j == 2) v2 = c; else v3 = c;
      float deg = (float)((double)(p & 0xFFFFFFFFFFFFull) * 2.3283064365386963e-10);
      dinvp[idx + j] = rsqrtf(deg);
    }
  }
  int tsum = v0 + v1 + v2 + v3;
  int inc = tsum;
  #pragma unroll
  for (int off = 1; off < 64; off <<= 1) {
    int u = __shfl_up(inc, off, 64);
    if (lane >= off) inc += u;
  }
  if (lane == 63) wsum[wv] = inc;
  __syncthreads();
  int woff = 0;
  for (int w2 = 0; w2 < wv; ++w2) woff += wsum[w2];
  int texc = woff + inc - tsum;
  if (idx     < n) rowstart[idx]     = texc;
  if (idx + 1 < n) rowstart[idx + 1] = texc + v0;
  if (idx + 2 < n) rowstart[idx + 2] = texc + v0 + v1;
  if (idx + 3 < n) rowstart[idx + 3] = texc + v0 + v1 + v2;
  if (tid == 255) {
    bsum[b] = woff + inc;
    // last block also owns rowstart[n] (block-local "one past last" = its total)
    if (b == (int)gridDim.x - 1) rowstart[n] = woff + inc;
  }
}

__global__ void scan2_kernel(const int* __restrict__ bsum, int* __restrict__ boff, int nblk) {
  __shared__ int wsum[4];
  int tid = threadIdx.x, lane = tid & 63, wv = tid >> 6;
  int v = (tid < nblk) ? bsum[tid] : 0;
  int inc = v;
  #pragma unroll
  for (int off = 1; off < 64; off <<= 1) {
    int u = __shfl_up(inc, off, 64);
    if (lane >= off) inc += u;
  }
  if (lane == 63) wsum[wv] = inc;
  __syncthreads();
  int woff = 0;
  for (int w2 = 0; w2 < wv; ++w2) woff += wsum[w2];
  if (tid < nblk) boff[tid] = woff + inc - v;
}

// ---- fill: erec[rowstart[d]+boff[d>>10]+rank] = (src, norm) -- no atomics ----
__global__ void fill_kernel(const int* __restrict__ src, const int* __restrict__ dst,
                            const float* __restrict__ w, const u16* __restrict__ rank,
                            const float* __restrict__ dinv, const int* __restrict__ rowstart,
                            const int* __restrict__ boff, int2* __restrict__ erec, int E) {
  int e = blockIdx.x * 256 + threadIdx.x;
  if (e < E) {
    int s = src[e], d = dst[e];
    int pos = rowstart[d] + boff[d >> 10] + (int)rank[e];
    float nrm = dinv[s] * w[e] * dinv[d];
    erec[pos] = make_int2(s, __float_as_int(nrm));
  }
}

// ---- gemm2: h2[M,64](bf16) = a1[M,128](bf16) @ W2[128,64] ----
__global__ __launch_bounds__(256) void gemm2_kernel(const u16* __restrict__ A,
                                                    const float* __restrict__ W,
                                                    u16* __restrict__ C, int M) {
  __shared__ float As[128][64];
  __shared__ float Ws[128][64];
  const int tid = threadIdx.x;
  const int tx = tid & 15;
  const int ty = tid >> 4;
  const int rowbase = blockIdx.x * 64;

  for (int i = tid; i < 64 * 32; i += 256) {
    int row = i & 63;
    int chunk = i >> 6;
    int k4 = chunk << 2;
    int gr = rowbase + row;
    float f0 = 0.f, f1 = 0.f, f2 = 0.f, f3 = 0.f;
    if (gr < M) {
      uint2 u = reinterpret_cast<const uint2*>(A + (size_t)gr * 128)[chunk];
      f0 = bflo(u.x); f1 = bfhi(u.x); f2 = bflo(u.y); f3 = bfhi(u.y);
    }
    As[k4 + 0][row] = f0;
    As[k4 + 1][row] = f1;
    As[k4 + 2][row] = f2;
    As[k4 + 3][row] = f3;
  }
  for (int i = tid; i < 128 * 16; i += 256) {
    int c4 = (i & 15) << 2;
    int k = i >> 4;
    float4 v = *reinterpret_cast<const float4*>(W + (size_t)k * 64 + c4);
    *reinterpret_cast<float4*>(&Ws[k][c4]) = v;
  }
  __syncthreads();

  float acc[4][4] = {};
  #pragma unroll 8
  for (int k = 0; k < 128; ++k) {
    float4 a = *reinterpret_cast<const float4*>(&As[k][ty << 2]);
    float4 b = *reinterpret_cast<const float4*>(&Ws[k][tx << 2]);
    acc[0][0] += a.x * b.x; acc[0][1] += a.x * b.y; acc[0][2] += a.x * b.z; acc[0][3] += a.x * b.w;
    acc[1][0] += a.y * b.x; acc[1][1] += a.y * b.y; acc[1][2] += a.y * b.z; acc[1][3] += a.y * b.w;
    acc[2][0] += a.z * b.x; acc[2][1] += a.z * b.y; acc[2][2] += a.z * b.z; acc[2][3] += a.z * b.w;
    acc[3][0] += a.w * b.x; acc[3][1] += a.w * b.y; acc[3][2] += a.w * b.z; acc[3][3] += a.w * b.w;
  }
  #pragma unroll
  for (int r = 0; r < 4; ++r) {
    int gr = rowbase + (ty << 2) + r;
    if (gr < M) {
      uint2 p;
      p.x = pack2bf(acc[r][0], acc[r][1]);
      p.y = pack2bf(acc[r][2], acc[r][3]);
      *reinterpret_cast<uint2*>(C + (size_t)gr * 64 + (tx << 2)) = p;
    }
  }
}

// ---- agg layer 1: bf16 gather (256B rows), 4-way unrolled, bf16 out ----
__global__ __launch_bounds__(256) void agg128_relu_kernel(
    const u32* __restrict__ H, const int* __restrict__ rowstart,
    const int* __restrict__ boff, const int2* __restrict__ erec,
    const float* __restrict__ dinv, const float* __restrict__ bias,
    u32* __restrict__ out, int n) {
  int wid = (blockIdx.x * 256 + threadIdx.x) >> 6;
  int lane = threadIdx.x & 63;
  if (wid >= n) return;
  float dv = dinv[wid];
  float ns = dv * dv;
  u32 hv = H[(size_t)wid * 64 + lane];
  float a0 = ns * bflo(hv), a1 = ns * bfhi(hv);
  int e0 = rowstart[wid] + boff[wid >> 10];
  int e1 = rowstart[wid + 1] + boff[(wid + 1) >> 10];
  int e = e0;
  for (; e + 3 < e1; e += 4) {
    int2 r0 = erec[e], r1 = erec[e + 1], r2 = erec[e + 2], r3 = erec[e + 3];
    u32 v0 = H[(size_t)r0.x * 64 + lane];
    u32 v1 = H[(size_t)r1.x * 64 + lane];
    u32 v2 = H[(size_t)r2.x * 64 + lane];
    u32 v3 = H[(size_t)r3.x * 64 + lane];
    float w0 = __int_as_float(r0.y), w1 = __int_as_float(r1.y);
    float w2 = __int_as_float(r2.y), w3 = __int_as_float(r3.y);
    a0 += w0 * bflo(v0) + w1 * bflo(v1) + w2 * bflo(v2) + w3 * bflo(v3);
    a1 += w0 * bfhi(v0) + w1 * bfhi(v1) + w2 * bfhi(v2) + w3 * bfhi(v3);
  }
  for (; e < e1; ++e) {
    int2 r = erec[e];
    u32 v = H[(size_t)r.x * 64 + lane];
    float w = __int_as_float(r.y);
    a0 += w * bflo(v);
    a1 += w * bfhi(v);
  }
  float2 bb = reinterpret_cast<const float2*>(bias)[lane];
  a0 = fmaxf(a0 + bb.x, 0.f);
  a1 = fmaxf(a1 + bb.y, 0.f);
  out[(size_t)wid * 64 + lane] = pack2bf(a0, a1);
}

// ---- agg layer 2: bf16 gather (128B rows), 4-way unrolled, fp32 out ----
__global__ __launch_bounds__(256) void agg64_kernel(
    const u16* __restrict__ H, const int* __restrict__ rowstart,
    const int* __restrict__ boff, const int2* __restrict__ erec,
    const float* __restrict__ dinv, const float* __restrict__ bias,
    float* __restrict__ out, int n) {
  int wid = (blockIdx.x * 256 + threadIdx.x) >> 6;
  int lane = threadIdx.x & 63;
  if (wid >= n) return;
  float dv = dinv[wid];
  float ns = dv * dv;
  float a0 = ns * bflo((u32)H[(size_t)wid * 64 + lane]);
  int e0 = rowstart[wid] + boff[wid >> 10];
  int e1 = rowstart[wid + 1] + boff[(wid + 1) >> 10];
  int e = e0;
  for (; e + 3 < e1; e += 4) {
    int2 r0 = erec[e], r1 = erec[e + 1], r2 = erec[e + 2], r3 = erec[e + 3];
    float v0 = bflo((u32)H[(size_t)r0.x * 64 + lane]);
    float v1 = bflo((u32)H[(size_t)r1.x * 64 + lane]);
    float v2 = bflo((u32)H[(size_t)r2.x * 64 + lane]);
    float v3 = bflo((u32)H[(size_t)r3.x * 64 + lane]);
    a0 += __int_as_float(r0.y) * v0 + __int_as_float(r1.y) * v1 +
          __int_as_float(r2.y) * v2 + __int_as_float(r3.y) * v3;
  }
  for (; e < e1; ++e) {
    int2 r = erec[e];
    a0 += __int_as_float(r.y) * bflo((u32)H[(size_t)r.x * 64 + lane]);
  }
  out[(size_t)wid * 64 + lane] = a0 + bias[lane];
}

extern "C" void kernel_launch(void* const* d_in, const int* in_sizes, int n_in,
                              void* d_out, int out_size, void* d_ws, size_t ws_size,
                              hipStream_t stream) {
  const float* x  = (const float*)d_in[0];
  const int*   ei = (const int*)d_in[1];
  const float* ew = (const float*)d_in[2];
  const float* W1 = (const float*)d_in[3];
  const float* b1 = (const float*)d_in[4];
  const float* W2 = (const float*)d_in[5];
  const float* b2 = (const float*)d_in[6];
  float* out = (float*)d_out;
  const int N = in_sizes[0] / 128;
  const int E = in_sizes[2];
  const int* src = ei;
  const int* dst = ei + E;

  char* wsB = (char*)d_ws;
  size_t off = 0;
  auto alloc = [&](size_t bytes) {
    void* p = wsB + off;
    off += ((bytes + 255) / 256) * 256;
    return p;
  };
  u64*   packed = (u64*)alloc((size_t)N * 8);
  float* dinv   = (float*)alloc((size_t)N * 4);
  u16*   rank   = (u16*)alloc((size_t)E * 2);
  int*   rowst  = (int*)alloc((size_t)(N + 1) * 4);
  int*   bsum   = (int*)alloc(256 * 4);
  int*   boff   = (int*)alloc(256 * 4);
  int2*  erec   = (int2*)alloc((size_t)E * 8);
  u16*   h1     = (u16*)alloc((size_t)N * 128 * 2);  // bf16
  u16*   a1     = (u16*)alloc((size_t)N * 128 * 2);  // bf16
  u16*   h2     = h1;  // h1 dead after agg1; reuse

  const int nb = (N + 255) / 256;
  const int eb = (E + 255) / 256;
  const int nbx = (N + 63) / 64;
  const int nblk = (N + 1023) / 1024;  // 98 <= 256

  init_kernel<<<nb, 256, 0, stream>>>(packed, N);
  degrank_kernel<<<eb, 256, 0, stream>>>(dst, ew, packed, rank, E);
  dim3 g1(nbx, 2);
  gemm1_kernel<<<g1, 256, 0, stream>>>(x, W1, h1, N);
  scan1_kernel<<<nblk, 256, 0, stream>>>(packed, rowst, bsum, dinv, N);
  scan2_kernel<<<1, 256, 0, stream>>>(bsum, boff, nblk);
  fill_kernel<<<eb, 256, 0, stream>>>(src, dst, ew, rank, dinv, rowst, boff, erec, E);

  const int ab = (N + 3) / 4;
  agg128_relu_kernel<<<ab, 256, 0, stream>>>((const u32*)h1, rowst, boff, erec, dinv, b1,
                                             (u32*)a1, N);
  gemm2_kernel<<<nbx, 256, 0, stream>>>(a1, W2, h2, N);
  agg64_kernel<<<ab, 256, 0, stream>>>(h2, rowst, boff, erec, dinv, b2, out, N);
}

// Round 11
// 432.129 us; speedup vs baseline: 1.0939x; 1.0939x over previous
//
#include <hip/hip_runtime.h>
#include <cstdint>
#include <cstddef>

// ---------------------------------------------------------------------------
// 2-layer GCN, bf16 intermediates. R10/R11:
//  - aggs: 2 nodes per wave (32 lanes x uint2/u32 per row) + 4-way unroll
//    -> 8 gather rows in flight per wave (R5/R9 showed latency-bound regime)
//  - gemms: bf16 MFMA 16x16x32. gemm1 uses split-A (x = hi+lo, 2 MFMAs) so
//    fp32 x loses nothing; W single bf16. A/B frags use the SAME k-bijection
//    so the MFMA dot is exact for any HW k-order; C/D map is the m89-verified
//    col=lane&15, row=(lane>>4)*4+reg.
//  - CSR build unchanged: 1 u64 atomic/edge (count|fixed-point deg) + rank.
// ---------------------------------------------------------------------------

typedef unsigned long long u64;
typedef unsigned int u32;
typedef unsigned short u16;
typedef __attribute__((ext_vector_type(8))) short bf16x8;
typedef __attribute__((ext_vector_type(4))) float f32x4;

__device__ __forceinline__ float bflo(u32 u) { return __uint_as_float(u << 16); }
__device__ __forceinline__ float bfhi(u32 u) { return __uint_as_float(u & 0xffff0000u); }
__device__ __forceinline__ u32 f2bf(float f) {  // round-to-nearest-even
  u32 u = __float_as_uint(f);
  return (u + 0x7fffu + ((u >> 16) & 1u)) >> 16;
}
__device__ __forceinline__ u32 pack2bf(float lo, float hi) {
  return f2bf(lo) | (f2bf(hi) << 16);
}

__global__ void init_kernel(u64* packed, int n) {
  int i = blockIdx.x * 256 + threadIdx.x;
  if (i < n) packed[i] = (1ull << 32);  // deg = 1.0 fixed-point, count = 0
}

__global__ void degrank_kernel(const int* __restrict__ dst, const float* __restrict__ w,
                               u64* packed, u16* __restrict__ rank, int E) {
  int e = blockIdx.x * 256 + threadIdx.x;
  if (e < E) {
    int d = dst[e];
    u64 add = (1ull << 48) | (u64)(w[e] * 4294967296.0f);
    u64 old = atomicAdd(&packed[d], add);
    rank[e] = (u16)(old >> 48);
  }
}

// ---- gemm1 (MFMA): h1[M,128](bf16) = x[M,128](fp32, split-A) @ W1[128,128] ----
__global__ __launch_bounds__(256) void gemm1_kernel(const float* __restrict__ x,
                                                    const float* __restrict__ W1,
                                                    u16* __restrict__ h1, int M) {
  __shared__ u16 Wt[128][136];  // [col][k], +8 pad; bf16
  const int tid = threadIdx.x;
  // stage W1 transposed; k-fast writes = conflict-free LDS
  for (int i = tid; i < 128 * 128; i += 256) {
    int c = i >> 7, k = i & 127;
    Wt[c][k] = (u16)f2bf(W1[(size_t)k * 128 + c]);
  }
  __syncthreads();

  const int wv = tid >> 6;
  const int l = tid & 63;
  const int c16 = l & 15;
  const int kg = l >> 4;
  const int arow = blockIdx.x * 64 + wv * 16 + c16;
  const bool rok = arow < M;

  bf16x8 ahi[4], alo[4];
  #pragma unroll
  for (int kk = 0; kk < 4; ++kk) {
    float v[8];
    if (rok) {
      float4 p0 = *reinterpret_cast<const float4*>(x + (size_t)arow * 128 + kk * 32 + kg * 8);
      float4 p1 = *reinterpret_cast<const float4*>(x + (size_t)arow * 128 + kk * 32 + kg * 8 + 4);
      v[0] = p0.x; v[1] = p0.y; v[2] = p0.z; v[3] = p0.w;
      v[4] = p1.x; v[5] = p1.y; v[6] = p1.z; v[7] = p1.w;
    } else {
      #pragma unroll
      for (int j = 0; j < 8; ++j) v[j] = 0.f;
    }
    #pragma unroll
    for (int j = 0; j < 8; ++j) {
      u32 hb = f2bf(v[j]);
      float hf = __uint_as_float(hb << 16);
      u32 lb = f2bf(v[j] - hf);
      ahi[kk][j] = (short)hb;
      alo[kk][j] = (short)lb;
    }
  }

  #pragma unroll
  for (int ct = 0; ct < 8; ++ct) {
    f32x4 acc = {0.f, 0.f, 0.f, 0.f};
    #pragma unroll
    for (int kk = 0; kk < 4; ++kk) {
      bf16x8 b = *reinterpret_cast<const bf16x8*>(&Wt[ct * 16 + c16][kk * 32 + kg * 8]);
      acc = __builtin_amdgcn_mfma_f32_16x16x32_bf16(alo[kk], b, acc, 0, 0, 0);
      acc = __builtin_amdgcn_mfma_f32_16x16x32_bf16(ahi[kk], b, acc, 0, 0, 0);
    }
    #pragma unroll
    for (int r = 0; r < 4; ++r) {
      int gr = blockIdx.x * 64 + wv * 16 + kg * 4 + r;
      if (gr < M) h1[(size_t)gr * 128 + ct * 16 + c16] = (u16)f2bf(acc[r]);
    }
  }
}

// ---- scan1 (+dinv): block-local exclusive scan of counts -> rowstart ----
__global__ void scan1_kernel(const u64* __restrict__ packed, int* __restrict__ rowstart,
                             int* __restrict__ bsum, float* __restrict__ dinvp, int n) {
  __shared__ int wsum[4];
  int b = blockIdx.x;
  int base = b * 1024;
  int tid = threadIdx.x;
  int lane = tid & 63, wv = tid >> 6;
  int idx = base + tid * 4;
  int v0 = 0, v1 = 0, v2 = 0, v3 = 0;
  #pragma unroll
  for (int j = 0; j < 4; ++j) {
    if (idx + j < n) {
      u64 p = packed[idx + j];
      int c = (int)(p >> 48);
      if (j == 0) v0 = c; else if (j == 1) v1 = c; else if (j == 2) v2 = c; else v3 = c;
      float deg = (float)((double)(p & 0xFFFFFFFFFFFFull) * 2.3283064365386963e-10);
      dinvp[idx + j] = rsqrtf(deg);
    }
  }
  int tsum = v0 + v1 + v2 + v3;
  int inc = tsum;
  #pragma unroll
  for (int off = 1; off < 64; off <<= 1) {
    int u = __shfl_up(inc, off, 64);
    if (lane >= off) inc += u;
  }
  if (lane == 63) wsum[wv] = inc;
  __syncthreads();
  int woff = 0;
  for (int w2 = 0; w2 < wv; ++w2) woff += wsum[w2];
  int texc = woff + inc - tsum;
  if (idx     < n) rowstart[idx]     = texc;
  if (idx + 1 < n) rowstart[idx + 1] = texc + v0;
  if (idx + 2 < n) rowstart[idx + 2] = texc + v0 + v1;
  if (idx + 3 < n) rowstart[idx + 3] = texc + v0 + v1 + v2;
  if (tid == 255) {
    bsum[b] = woff + inc;
    if (b == (int)gridDim.x - 1) rowstart[n] = woff + inc;
  }
}

__global__ void scan2_kernel(const int* __restrict__ bsum, int* __restrict__ boff, int nblk) {
  __shared__ int wsum[4];
  int tid = threadIdx.x, lane = tid & 63, wv = tid >> 6;
  int v = (tid < nblk) ? bsum[tid] : 0;
  int inc = v;
  #pragma unroll
  for (int off = 1; off < 64; off <<= 1) {
    int u = __shfl_up(inc, off, 64);
    if (lane >= off) inc += u;
  }
  if (lane == 63) wsum[wv] = inc;
  __syncthreads();
  int woff = 0;
  for (int w2 = 0; w2 < wv; ++w2) woff += wsum[w2];
  if (tid < nblk) boff[tid] = woff + inc - v;
}

// ---- fill: erec[rowstart[d]+boff[d>>10]+rank] = (src, norm) -- no atomics ----
__global__ void fill_kernel(const int* __restrict__ src, const int* __restrict__ dst,
                            const float* __restrict__ w, const u16* __restrict__ rank,
                            const float* __restrict__ dinv, const int* __restrict__ rowstart,
                            const int* __restrict__ boff, int2* __restrict__ erec, int E) {
  int e = blockIdx.x * 256 + threadIdx.x;
  if (e < E) {
    int s = src[e], d = dst[e];
    int pos = rowstart[d] + boff[d >> 10] + (int)rank[e];
    float nrm = dinv[s] * w[e] * dinv[d];
    erec[pos] = make_int2(s, __float_as_int(nrm));
  }
}

// ---- gemm2 (MFMA): h2[M,64](bf16) = a1[M,128](bf16) @ W2[128,64] ----
__global__ __launch_bounds__(256) void gemm2_kernel(const u16* __restrict__ A,
                                                    const float* __restrict__ W2,
                                                    u16* __restrict__ C, int M) {
  __shared__ u16 Wt[64][136];  // [col][k], +8 pad; bf16
  const int tid = threadIdx.x;
  for (int i = tid; i < 128 * 64; i += 256) {
    int c = i >> 7, k = i & 127;
    Wt[c][k] = (u16)f2bf(W2[(size_t)k * 64 + c]);
  }
  __syncthreads();

  const int wv = tid >> 6;
  const int l = tid & 63;
  const int c16 = l & 15;
  const int kg = l >> 4;
  const int arow = blockIdx.x * 64 + wv * 16 + c16;
  const bool rok = arow < M;

  bf16x8 af[4];
  #pragma unroll
  for (int kk = 0; kk < 4; ++kk) {
    if (rok) {
      af[kk] = *reinterpret_cast<const bf16x8*>(A + (size_t)arow * 128 + kk * 32 + kg * 8);
    } else {
      af[kk] = bf16x8{0, 0, 0, 0, 0, 0, 0, 0};
    }
  }

  #pragma unroll
  for (int ct = 0; ct < 4; ++ct) {
    f32x4 acc = {0.f, 0.f, 0.f, 0.f};
    #pragma unroll
    for (int kk = 0; kk < 4; ++kk) {
      bf16x8 b = *reinterpret_cast<const bf16x8*>(&Wt[ct * 16 + c16][kk * 32 + kg * 8]);
      acc = __builtin_amdgcn_mfma_f32_16x16x32_bf16(af[kk], b, acc, 0, 0, 0);
    }
    #pragma unroll
    for (int r = 0; r < 4; ++r) {
      int gr = blockIdx.x * 64 + wv * 16 + kg * 4 + r;
      if (gr < M) C[(size_t)gr * 64 + ct * 16 + c16] = (u16)f2bf(acc[r]);
    }
  }
}

// ---- agg layer 1: 2 nodes/wave, 32 lanes x uint2 (256B row), 4-way unroll ----
__global__ __launch_bounds__(256) void agg128_relu_kernel(
    const uint2* __restrict__ H2, const int* __restrict__ rowstart,
    const int* __restrict__ boff, const int2* __restrict__ erec,
    const float* __restrict__ dinv, const float* __restrict__ bias,
    uint2* __restrict__ out2, int n) {
  int wid = (blockIdx.x * 256 + threadIdx.x) >> 6;
  int lane = threadIdx.x & 63;
  int node = wid * 2 + (lane >> 5);
  int hl = lane & 31;
  if (node >= n) return;
  float dv = dinv[node];
  float ns = dv * dv;
  uint2 hv = H2[(size_t)node * 32 + hl];
  float a0 = ns * bflo(hv.x), a1 = ns * bfhi(hv.x);
  float a2 = ns * bflo(hv.y), a3 = ns * bfhi(hv.y);
  int e  = rowstart[node] + boff[node >> 10];
  int e1 = rowstart[node + 1] + boff[(node + 1) >> 10];
  for (; e + 3 < e1; e += 4) {
    int2 r0 = erec[e], r1 = erec[e + 1], r2 = erec[e + 2], r3 = erec[e + 3];
    uint2 v0 = H2[(size_t)r0.x * 32 + hl];
    uint2 v1 = H2[(size_t)r1.x * 32 + hl];
    uint2 v2 = H2[(size_t)r2.x * 32 + hl];
    uint2 v3 = H2[(size_t)r3.x * 32 + hl];
    float w0 = __int_as_float(r0.y), w1 = __int_as_float(r1.y);
    float w2 = __int_as_float(r2.y), w3 = __int_as_float(r3.y);
    a0 += w0 * bflo(v0.x) + w1 * bflo(v1.x) + w2 * bflo(v2.x) + w3 * bflo(v3.x);
    a1 += w0 * bfhi(v0.x) + w1 * bfhi(v1.x) + w2 * bfhi(v2.x) + w3 * bfhi(v3.x);
    a2 += w0 * bflo(v0.y) + w1 * bflo(v1.y) + w2 * bflo(v2.y) + w3 * bflo(v3.y);
    a3 += w0 * bfhi(v0.y) + w1 * bfhi(v1.y) + w2 * bfhi(v2.y) + w3 * bfhi(v3.y);
  }
  for (; e < e1; ++e) {
    int2 r = erec[e];
    uint2 v = H2[(size_t)r.x * 32 + hl];
    float w = __int_as_float(r.y);
    a0 += w * bflo(v.x); a1 += w * bfhi(v.x);
    a2 += w * bflo(v.y); a3 += w * bfhi(v.y);
  }
  float4 bb = reinterpret_cast<const float4*>(bias)[hl];
  a0 = fmaxf(a0 + bb.x, 0.f);
  a1 = fmaxf(a1 + bb.y, 0.f);
  a2 = fmaxf(a2 + bb.z, 0.f);
  a3 = fmaxf(a3 + bb.w, 0.f);
  out2[(size_t)node * 32 + hl] = make_uint2(pack2bf(a0, a1), pack2bf(a2, a3));
}

// ---- agg layer 2: 2 nodes/wave, 32 lanes x u32 (128B row), 4-way unroll ----
__global__ __launch_bounds__(256) void agg64_kernel(
    const u32* __restrict__ H, const int* __restrict__ rowstart,
    const int* __restrict__ boff, const int2* __restrict__ erec,
    const float* __restrict__ dinv, const float* __restrict__ bias,
    float2* __restrict__ out2, int n) {
  int wid = (blockIdx.x * 256 + threadIdx.x) >> 6;
  int lane = threadIdx.x & 63;
  int node = wid * 2 + (lane >> 5);
  int hl = lane & 31;
  if (node >= n) return;
  float dv = dinv[node];
  float ns = dv * dv;
  u32 hv = H[(size_t)node * 32 + hl];
  float a0 = ns * bflo(hv), a1 = ns * bfhi(hv);
  int e  = rowstart[node] + boff[node >> 10];
  int e1 = rowstart[node + 1] + boff[(node + 1) >> 10];
  for (; e + 3 < e1; e += 4) {
    int2 r0 = erec[e], r1 = erec[e + 1], r2 = erec[e + 2], r3 = erec[e + 3];
    u32 v0 = H[(size_t)r0.x * 32 + hl];
    u32 v1 = H[(size_t)r1.x * 32 + hl];
    u32 v2 = H[(size_t)r2.x * 32 + hl];
    u32 v3 = H[(size_t)r3.x * 32 + hl];
    a0 += __int_as_float(r0.y) * bflo(v0) + __int_as_float(r1.y) * bflo(v1)
        + __int_as_float(r2.y) * bflo(v2) + __int_as_float(r3.y) * bflo(v3);
    a1 += __int_as_float(r0.y) * bfhi(v0) + __int_as_float(r1.y) * bfhi(v1)
        + __int_as_float(r2.y) * bfhi(v2) + __int_as_float(r3.y) * bfhi(v3);
  }
  for (; e < e1; ++e) {
    int2 r = erec[e];
    u32 v = H[(size_t)r.x * 32 + hl];
    float w = __int_as_float(r.y);
    a0 += w * bflo(v);
    a1 += w * bfhi(v);
  }
  float2 bb = reinterpret_cast<const float2*>(bias)[hl];
  out2[(size_t)node * 32 + hl] = make_float2(a0 + bb.x, a1 + bb.y);
}

extern "C" void kernel_launch(void* const* d_in, const int* in_sizes, int n_in,
                              void* d_out, int out_size, void* d_ws, size_t ws_size,
                              hipStream_t stream) {
  const float* x  = (const float*)d_in[0];
  const int*   ei = (const int*)d_in[1];
  const float* ew = (const float*)d_in[2];
  const float* W1 = (const float*)d_in[3];
  const float* b1 = (const float*)d_in[4];
  const float* W2 = (const float*)d_in[5];
  const float* b2 = (const float*)d_in[6];
  float* out = (float*)d_out;
  const int N = in_sizes[0] / 128;
  const int E = in_sizes[2];
  const int* src = ei;
  const int* dst = ei + E;

  char* wsB = (char*)d_ws;
  size_t off = 0;
  auto alloc = [&](size_t bytes) {
    void* p = wsB + off;
    off += ((bytes + 255) / 256) * 256;
    return p;
  };
  u64*   packed = (u64*)alloc((size_t)N * 8);
  float* dinv   = (float*)alloc((size_t)N * 4);
  u16*   rank   = (u16*)alloc((size_t)E * 2);
  int*   rowst  = (int*)alloc((size_t)(N + 1) * 4);
  int*   bsum   = (int*)alloc(256 * 4);
  int*   boff   = (int*)alloc(256 * 4);
  int2*  erec   = (int2*)alloc((size_t)E * 8);
  u16*   h1     = (u16*)alloc((size_t)N * 128 * 2);  // bf16
  u16*   a1     = (u16*)alloc((size_t)N * 128 * 2);  // bf16
  u16*   h2     = h1;  // h1 dead after agg1; reuse

  const int nb = (N + 255) / 256;
  const int eb = (E + 255) / 256;
  const int nbx = (N + 63) / 64;
  const int nblk = (N + 1023) / 1024;  // 98 <= 256

  init_kernel<<<nb, 256, 0, stream>>>(packed, N);
  degrank_kernel<<<eb, 256, 0, stream>>>(dst, ew, packed, rank, E);
  gemm1_kernel<<<nbx, 256, 0, stream>>>(x, W1, h1, N);
  scan1_kernel<<<nblk, 256, 0, stream>>>(packed, rowst, bsum, dinv, N);
  scan2_kernel<<<1, 256, 0, stream>>>(bsum, boff, nblk);
  fill_kernel<<<eb, 256, 0, stream>>>(src, dst, ew, rank, dinv, rowst, boff, erec, E);

  const int ab = (N + 7) / 8;  // 2 nodes/wave, 8 nodes/block
  agg128_relu_kernel<<<ab, 256, 0, stream>>>((const uint2*)h1, rowst, boff, erec, dinv, b1,
                                             (uint2*)a1, N);
  gemm2_kernel<<<nbx, 256, 0, stream>>>(a1, W2, h2, N);
  agg64_kernel<<<ab, 256, 0, stream>>>((const u32*)h2, rowst, boff, erec, dinv, b2,
                                       (float2*)out, N);
}